// Round 20
// baseline (286.605 us; speedup 1.0000x reference)
//
#include <hip/hip_runtime.h>
#include <hip/hip_fp16.h>

#define DF 128
#define RB 512            // nodes per bucket (power of two)
#define RB_SHIFT 9
#define NB_MAX 256        // supports n <= 131072
#define CHUNK 8192        // edges per binning block (2048 measured worse, R16)

struct h2x4 { __half2 a, b, c, d; }; // 16 bytes = 8 halves

typedef _Float16 hh2 __attribute__((ext_vector_type(2)));
struct alignas(16) hv8 { hh2 a, b, c, d; };   // 16 bytes = 8 halves

typedef _Float16 f16x8 __attribute__((ext_vector_type(8)));
typedef float f32x4 __attribute__((ext_vector_type(4)));

// ---------------- init: transpose W0,W1 -> fp16 WT, zero bcnt/bcur ----------------

__global__ void k_init(const float* __restrict__ W0, const float* __restrict__ W1,
                       __half* __restrict__ WT0h, __half* __restrict__ WT1h,
                       int* __restrict__ bcnt, int* __restrict__ bcur){
  int t = threadIdx.x;
  if(blockIdx.x==0) bcnt[t]=0;
  if(blockIdx.x==1) bcur[t]=0;
  int i = blockIdx.x*256 + t;            // 0..32767
  int k = (i&16383)>>7, c = i&127;
  if(i<16384) WT0h[(size_t)c*DF+k] = __float2half(W0[(size_t)k*DF+c]);
  else        WT1h[(size_t)c*DF+k] = __float2half(W1[(size_t)k*DF+c]);
}

// ---------------- CSR build (bucketed, coalesced; binned packed: (s<<9)|(d&511)) ----------------

__global__ void k_bhist(const int* __restrict__ dst, int* __restrict__ bcnt, int e){
  __shared__ int h[NB_MAX];
  int t = threadIdx.x;
  h[t] = 0;
  __syncthreads();
  int base = blockIdx.x*CHUNK;
  for(int k=0;k<CHUNK/256;k++){
    int i = base + t + k*256;
    if(i<e) atomicAdd(&h[dst[i]>>RB_SHIFT], 1);
  }
  __syncthreads();
  if(h[t]) atomicAdd(&bcnt[t], h[t]);
}

__launch_bounds__(256)
__global__ void k_binscatter(const int* __restrict__ src, const int* __restrict__ dst,
                             const int* __restrict__ bcnt, int* __restrict__ bcur,
                             int* __restrict__ binned, int e){
  __shared__ int h[NB_MAX];
  __shared__ int lexcl[NB_MAX];
  __shared__ int lcur[NB_MAX];
  __shared__ int gbase[NB_MAX];
  __shared__ int gscn[NB_MAX];
  __shared__ int2 pairs[CHUNK];
  int t = threadIdx.x;
  int c0 = blockIdx.x*CHUNK;
  int cc = min(CHUNK, e - c0);
  h[t]=0;
  int gc = bcnt[t];
  gscn[t] = gc;
  __syncthreads();
  for(int off=1; off<256; off<<=1){
    int v = (t>=off)? gscn[t-off]:0;
    __syncthreads();
    gscn[t]+=v;
    __syncthreads();
  }
  int gex = gscn[t] - gc;
  for(int k=0;k<CHUNK/256;k++){
    int i = t + k*256;
    if(i<cc) atomicAdd(&h[dst[c0+i]>>RB_SHIFT], 1);
  }
  __syncthreads();
  int hc = h[t];
  lexcl[t]=hc;
  __syncthreads();
  for(int off=1; off<256; off<<=1){
    int v = (t>=off)? lexcl[t-off]:0;
    __syncthreads();
    lexcl[t]+=v;
    __syncthreads();
  }
  int incl = lexcl[t];
  lexcl[t] = incl - hc;
  lcur[t]  = incl - hc;
  gbase[t] = hc ? (gex + atomicAdd(&bcur[t], hc)) : 0;
  __syncthreads();
  for(int k=0;k<CHUNK/256;k++){
    int i = t + k*256;
    if(i<cc){
      int d = dst[c0+i], s = src[c0+i];
      int lp = atomicAdd(&lcur[d>>RB_SHIFT], 1);
      pairs[lp] = make_int2(d, s);
    }
  }
  __syncthreads();
  for(int k=0;k<CHUNK/256;k++){
    int p = t + k*256;
    if(p<cc){
      int2 pr = pairs[p];
      int b = pr.x>>RB_SHIFT;
      int packed = (pr.y<<RB_SHIFT) | (pr.x & (RB-1));
      binned[gbase[b] + (p - lexcl[b])] = packed;
    }
  }
}

__launch_bounds__(256)
__global__ void k_localcsr(const int* __restrict__ binned, const int* __restrict__ bcnt,
                           int* __restrict__ rp, int* __restrict__ csr,
                           float* __restrict__ dinv, int n, int e){
  __shared__ int cnt[RB];
  __shared__ int sh[256];
  __shared__ int cur[RB];
  __shared__ int sb[257];
  int b = blockIdx.x, t = threadIdx.x;
  int node0 = b<<RB_SHIFT;
  int gc = bcnt[t];
  sh[t] = gc;
  __syncthreads();
  for(int off=1; off<256; off<<=1){
    int v = (t>=off)? sh[t-off]:0;
    __syncthreads();
    sh[t]+=v;
    __syncthreads();
  }
  sb[t+1]=sh[t];
  if(t==0) sb[0]=0;
  __syncthreads();
  int e0 = sb[b], e1 = sb[b+1];
  cnt[t]=0; cnt[t+256]=0;
  __syncthreads();
  for(int i=e0+t; i<e1; i+=256)
    atomicAdd(&cnt[binned[i] & (RB-1)], 1);
  __syncthreads();
  int c0 = cnt[2*t], c1 = cnt[2*t+1];
  int s = c0+c1;
  sh[t]=s;
  __syncthreads();
  for(int off=1; off<256; off<<=1){
    int v = (t>=off)? sh[t-off]:0;
    __syncthreads();
    sh[t]+=v;
    __syncthreads();
  }
  int excl = sh[t]-s;
  int g0 = node0+2*t, g1 = node0+2*t+1;
  if(g0<n){ rp[g0]=e0+excl;    dinv[g0]=rsqrtf((float)(c0+1)); }
  if(g1<n){ rp[g1]=e0+excl+c0; dinv[g1]=rsqrtf((float)(c1+1)); }
  cur[2*t]=excl; cur[2*t+1]=excl+c0;
  if(b==0 && t==0) rp[n]=e;
  __syncthreads();
  for(int i=e0+t; i<e1; i+=256){
    int pk = binned[i];
    int lp = atomicAdd(&cur[pk & (RB-1)], 1);
    csr[e0+lp] = ((unsigned)pk) >> RB_SHIFT;
  }
}

// ---------------- GEMM via MFMA: ht = dinv .* (X @ W) -> fp16 ----------------
// 128 rows/block, 512 threads (8 waves). X staged in LDS (34.8KB -> 4 blocks/CU);
// B fragments read directly from global WTh (32KB, L1/L2-resident).
// Epilogue transposes D through xsh (freed after MFMA) -> coalesced 16B stores.

template<bool IN_HALF>
__launch_bounds__(512)
__global__ void k_gemm128m(const void* __restrict__ Xp, const __half* __restrict__ WTh,
                           const float* __restrict__ dinv, __half* __restrict__ out, int n){
  __shared__ hh2 xsh[128][68];   // 128 rows x 136 halves (pad -> 2-way bank, free)
  int t = threadIdx.x;
  int row0 = blockIdx.x*128;
  for(int idx=t; idx<128*16; idx+=512){
    int r = idx>>4, k8 = idx&15;
    int gr = row0+r;
    hv8 u;
    if(gr<n){
      if constexpr(IN_HALF){
        u = *(const hv8*)((const __half*)Xp + (size_t)gr*DF + k8*8);
      } else {
        const float* xp = (const float*)Xp + (size_t)gr*DF + k8*8;
        float4 v0 = *(const float4*)xp;
        float4 v1 = *(const float4*)(xp+4);
        u.a = hh2{(_Float16)v0.x,(_Float16)v0.y};
        u.b = hh2{(_Float16)v0.z,(_Float16)v0.w};
        u.c = hh2{(_Float16)v1.x,(_Float16)v1.y};
        u.d = hh2{(_Float16)v1.z,(_Float16)v1.w};
      }
    } else {
      u.a = hh2{0,0}; u.b = u.a; u.c = u.a; u.d = u.a;
    }
    *(hv8*)&xsh[r][k8*4] = u;
  }
  __syncthreads();
  int wave = t>>6, lane = t&63;
  int lrow = lane&15, lk = lane>>4;
  f32x4 acc[8];
  #pragma unroll
  for(int i=0;i<8;i++) acc[i] = (f32x4){0.f,0.f,0.f,0.f};
  #pragma unroll
  for(int kc=0;kc<4;kc++){
    int koff = kc*16 + lk*4;                 // hh2 units
    f16x8 afr = *(const f16x8*)&xsh[wave*16 + lrow][koff];
    #pragma unroll
    for(int nt=0;nt<8;nt++){
      f16x8 bfr = *(const f16x8*)(WTh + (size_t)(nt*16+lrow)*DF + kc*32 + lk*8);
      acc[nt] = __builtin_amdgcn_mfma_f32_16x16x32_f16(afr, bfr, acc[nt], 0, 0, 0);
    }
  }
  __syncthreads();   // xsh reads done; safe to overwrite
  __half* xh = (__half*)&xsh[0][0];    // row stride 136 halves
  int brow = wave*16 + lk*4;
  #pragma unroll
  for(int r=0;r<4;r++){
    int gr = row0 + brow + r;
    float dv = (gr<n)? dinv[gr] : 0.f;
    #pragma unroll
    for(int nt=0;nt<8;nt++){
      xh[(size_t)(brow+r)*136 + nt*16 + lrow] = __float2half(dv*acc[nt][r]);
    }
  }
  __syncthreads();
  for(int idx=t; idx<128*16; idx+=512){
    int r = idx>>4, k8 = idx&15;
    int gr = row0+r;
    if(gr<n) *(hv8*)(out + (size_t)gr*DF + k8*8) = *(const hv8*)&xsh[r][k8*4];
  }
}

// ---------------- Layer-1 aggregate (fp16 gather -> fp16 out) ----------------

__launch_bounds__(256)
__global__ void k_agg128h(const __half* __restrict__ ht, const int* __restrict__ rp,
                          const int* __restrict__ cs, const float* __restrict__ dinv,
                          const float* __restrict__ bias, __half* __restrict__ outp, int n){
  int t=threadIdx.x;
  int node = blockIdx.x*16 + (t>>4);
  if(node>=n) return;
  int l8 = (t&15)*8;
  h2x4 sv = *(const h2x4*)(ht + (size_t)node*DF + l8);   // self
  float2 P0=__half22float2(sv.a), P1=__half22float2(sv.b),
         P2=__half22float2(sv.c), P3=__half22float2(sv.d);
  float2 Q0=make_float2(0.f,0.f), Q1=Q0, Q2=Q0, Q3=Q0;
  int e0=rp[node], e1=rp[node+1];
  int e=e0;
  for(; e+3<e1; e+=4){
    int s0=cs[e], s1=cs[e+1], s2=cs[e+2], s3=cs[e+3];
    h2x4 u0 = *(const h2x4*)(ht + (size_t)s0*DF + l8);
    h2x4 u1 = *(const h2x4*)(ht + (size_t)s1*DF + l8);
    h2x4 u2 = *(const h2x4*)(ht + (size_t)s2*DF + l8);
    h2x4 u3 = *(const h2x4*)(ht + (size_t)s3*DF + l8);
    float2 f;
    f=__half22float2(u0.a); P0.x+=f.x; P0.y+=f.y;
    f=__half22float2(u0.b); P1.x+=f.x; P1.y+=f.y;
    f=__half22float2(u0.c); P2.x+=f.x; P2.y+=f.y;
    f=__half22float2(u0.d); P3.x+=f.x; P3.y+=f.y;
    f=__half22float2(u1.a); Q0.x+=f.x; Q0.y+=f.y;
    f=__half22float2(u1.b); Q1.x+=f.x; Q1.y+=f.y;
    f=__half22float2(u1.c); Q2.x+=f.x; Q2.y+=f.y;
    f=__half22float2(u1.d); Q3.x+=f.x; Q3.y+=f.y;
    f=__half22float2(u2.a); P0.x+=f.x; P0.y+=f.y;
    f=__half22float2(u2.b); P1.x+=f.x; P1.y+=f.y;
    f=__half22float2(u2.c); P2.x+=f.x; P2.y+=f.y;
    f=__half22float2(u2.d); P3.x+=f.x; P3.y+=f.y;
    f=__half22float2(u3.a); Q0.x+=f.x; Q0.y+=f.y;
    f=__half22float2(u3.b); Q1.x+=f.x; Q1.y+=f.y;
    f=__half22float2(u3.c); Q2.x+=f.x; Q2.y+=f.y;
    f=__half22float2(u3.d); Q3.x+=f.x; Q3.y+=f.y;
  }
  for(; e<e1; e++){
    h2x4 u0 = *(const h2x4*)(ht + (size_t)cs[e]*DF + l8);
    float2 f;
    f=__half22float2(u0.a); P0.x+=f.x; P0.y+=f.y;
    f=__half22float2(u0.b); P1.x+=f.x; P1.y+=f.y;
    f=__half22float2(u0.c); P2.x+=f.x; P2.y+=f.y;
    f=__half22float2(u0.d); P3.x+=f.x; P3.y+=f.y;
  }
  float dv=dinv[node];
  const float4 bz0 = *(const float4*)(bias + l8);
  const float4 bz1 = *(const float4*)(bias + l8 + 4);
  float4 o0, o1;
  o0.x = fmaxf(fmaf(dv, P0.x+Q0.x, bz0.x), 0.f);
  o0.y = fmaxf(fmaf(dv, P0.y+Q0.y, bz0.y), 0.f);
  o0.z = fmaxf(fmaf(dv, P1.x+Q1.x, bz0.z), 0.f);
  o0.w = fmaxf(fmaf(dv, P1.y+Q1.y, bz0.w), 0.f);
  o1.x = fmaxf(fmaf(dv, P2.x+Q2.x, bz1.x), 0.f);
  o1.y = fmaxf(fmaf(dv, P2.y+Q2.y, bz1.y), 0.f);
  o1.z = fmaxf(fmaf(dv, P3.x+Q3.x, bz1.z), 0.f);
  o1.w = fmaxf(fmaf(dv, P3.y+Q3.y, bz1.w), 0.f);
  h2x4 st;
  st.a = __floats2half2_rn(o0.x, o0.y);
  st.b = __floats2half2_rn(o0.z, o0.w);
  st.c = __floats2half2_rn(o1.x, o1.y);
  st.d = __floats2half2_rn(o1.z, o1.w);
  *(h2x4*)(outp + (size_t)node*DF + l8) = st;
}

// ---------------- Layer-2 aggregate fused with W2: ht8 = dinv*(relu(...)@W2) ----------------

__launch_bounds__(256)
__global__ void k_agg_w2(const __half* __restrict__ ht, const int* __restrict__ rp,
                         const int* __restrict__ cs, const float* __restrict__ dinv,
                         const float* __restrict__ bias, const float* __restrict__ W2,
                         float* __restrict__ ht8, int n){
  int t=threadIdx.x;
  int node = blockIdx.x*16 + (t>>4);
  if(node>=n) return;
  int l8 = (t&15)*8;
  h2x4 sv = *(const h2x4*)(ht + (size_t)node*DF + l8);   // self
  float2 P0=__half22float2(sv.a), P1=__half22float2(sv.b),
         P2=__half22float2(sv.c), P3=__half22float2(sv.d);
  float2 Q0=make_float2(0.f,0.f), Q1=Q0, Q2=Q0, Q3=Q0;
  int e0=rp[node], e1=rp[node+1];
  int e=e0;
  for(; e+3<e1; e+=4){
    int s0=cs[e], s1=cs[e+1], s2=cs[e+2], s3=cs[e+3];
    h2x4 u0 = *(const h2x4*)(ht + (size_t)s0*DF + l8);
    h2x4 u1 = *(const h2x4*)(ht + (size_t)s1*DF + l8);
    h2x4 u2 = *(const h2x4*)(ht + (size_t)s2*DF + l8);
    h2x4 u3 = *(const h2x4*)(ht + (size_t)s3*DF + l8);
    float2 f;
    f=__half22float2(u0.a); P0.x+=f.x; P0.y+=f.y;
    f=__half22float2(u0.b); P1.x+=f.x; P1.y+=f.y;
    f=__half22float2(u0.c); P2.x+=f.x; P2.y+=f.y;
    f=__half22float2(u0.d); P3.x+=f.x; P3.y+=f.y;
    f=__half22float2(u1.a); Q0.x+=f.x; Q0.y+=f.y;
    f=__half22float2(u1.b); Q1.x+=f.x; Q1.y+=f.y;
    f=__half22float2(u1.c); Q2.x+=f.x; Q2.y+=f.y;
    f=__half22float2(u1.d); Q3.x+=f.x; Q3.y+=f.y;
    f=__half22float2(u2.a); P0.x+=f.x; P0.y+=f.y;
    f=__half22float2(u2.b); P1.x+=f.x; P1.y+=f.y;
    f=__half22float2(u2.c); P2.x+=f.x; P2.y+=f.y;
    f=__half22float2(u2.d); P3.x+=f.x; P3.y+=f.y;
    f=__half22float2(u3.a); Q0.x+=f.x; Q0.y+=f.y;
    f=__half22float2(u3.b); Q1.x+=f.x; Q1.y+=f.y;
    f=__half22float2(u3.c); Q2.x+=f.x; Q2.y+=f.y;
    f=__half22float2(u3.d); Q3.x+=f.x; Q3.y+=f.y;
  }
  for(; e<e1; e++){
    h2x4 u0 = *(const h2x4*)(ht + (size_t)cs[e]*DF + l8);
    float2 f;
    f=__half22float2(u0.a); P0.x+=f.x; P0.y+=f.y;
    f=__half22float2(u0.b); P1.x+=f.x; P1.y+=f.y;
    f=__half22float2(u0.c); P2.x+=f.x; P2.y+=f.y;
    f=__half22float2(u0.d); P3.x+=f.x; P3.y+=f.y;
  }
  float dv=dinv[node];
  const float4 bz0 = *(const float4*)(bias + l8);
  const float4 bz1 = *(const float4*)(bias + l8 + 4);
  float h0 = fmaxf(fmaf(dv, P0.x+Q0.x, bz0.x), 0.f);
  float h1 = fmaxf(fmaf(dv, P0.y+Q0.y, bz0.y), 0.f);
  float h2 = fmaxf(fmaf(dv, P1.x+Q1.x, bz0.z), 0.f);
  float h3 = fmaxf(fmaf(dv, P1.y+Q1.y, bz0.w), 0.f);
  float h4 = fmaxf(fmaf(dv, P2.x+Q2.x, bz1.x), 0.f);
  float h5 = fmaxf(fmaf(dv, P2.y+Q2.y, bz1.y), 0.f);
  float h6 = fmaxf(fmaf(dv, P3.x+Q3.x, bz1.z), 0.f);
  float h7 = fmaxf(fmaf(dv, P3.y+Q3.y, bz1.w), 0.f);
  const float* w2r = W2 + (size_t)l8*5;
  float p0,p1,p2,p3,p4;
  p0 = h0*w2r[0];  p1 = h0*w2r[1];  p2 = h0*w2r[2];  p3 = h0*w2r[3];  p4 = h0*w2r[4];
  p0 = fmaf(h1,w2r[5], p0); p1 = fmaf(h1,w2r[6], p1); p2 = fmaf(h1,w2r[7], p2); p3 = fmaf(h1,w2r[8], p3); p4 = fmaf(h1,w2r[9], p4);
  p0 = fmaf(h2,w2r[10],p0); p1 = fmaf(h2,w2r[11],p1); p2 = fmaf(h2,w2r[12],p2); p3 = fmaf(h2,w2r[13],p3); p4 = fmaf(h2,w2r[14],p4);
  p0 = fmaf(h3,w2r[15],p0); p1 = fmaf(h3,w2r[16],p1); p2 = fmaf(h3,w2r[17],p2); p3 = fmaf(h3,w2r[18],p3); p4 = fmaf(h3,w2r[19],p4);
  p0 = fmaf(h4,w2r[20],p0); p1 = fmaf(h4,w2r[21],p1); p2 = fmaf(h4,w2r[22],p2); p3 = fmaf(h4,w2r[23],p3); p4 = fmaf(h4,w2r[24],p4);
  p0 = fmaf(h5,w2r[25],p0); p1 = fmaf(h5,w2r[26],p1); p2 = fmaf(h5,w2r[27],p2); p3 = fmaf(h5,w2r[28],p3); p4 = fmaf(h5,w2r[29],p4);
  p0 = fmaf(h6,w2r[30],p0); p1 = fmaf(h6,w2r[31],p1); p2 = fmaf(h6,w2r[32],p2); p3 = fmaf(h6,w2r[33],p3); p4 = fmaf(h6,w2r[34],p4);
  p0 = fmaf(h7,w2r[35],p0); p1 = fmaf(h7,w2r[36],p1); p2 = fmaf(h7,w2r[37],p2); p3 = fmaf(h7,w2r[38],p3); p4 = fmaf(h7,w2r[39],p4);
  #pragma unroll
  for(int off=8; off>=1; off>>=1){
    p0 += __shfl_xor(p0, off, 16);
    p1 += __shfl_xor(p1, off, 16);
    p2 += __shfl_xor(p2, off, 16);
    p3 += __shfl_xor(p3, off, 16);
    p4 += __shfl_xor(p4, off, 16);
  }
  if((t&15)==0){
    float* ob = ht8 + (size_t)node*8;
    *(float4*)ob     = make_float4(dv*p0, dv*p1, dv*p2, dv*p3);
    *(float4*)(ob+4) = make_float4(dv*p4, 0.f, 0.f, 0.f);
  }
}

// ---------------- Final aggregate: 2 threads/node, float4 from padded L2-resident ht8 ----------------

__global__ void k_agg5(const float* __restrict__ ht8, const int* __restrict__ rp,
                       const int* __restrict__ cs, const float* __restrict__ dinv,
                       const float* __restrict__ b2, float* __restrict__ out, int n){
  int idx = blockIdx.x*256+threadIdx.x;
  int node = idx>>1, half = idx&1;
  if(node>=n) return;
  float4 acc = *(const float4*)(ht8 + (size_t)node*8 + half*4);
  int e0=rp[node], e1=rp[node+1];
  int e=e0;
  float4 acc2 = make_float4(0.f,0.f,0.f,0.f);
  for(; e+1<e1; e+=2){
    float4 v0 = *(const float4*)(ht8 + (size_t)cs[e  ]*8 + half*4);
    float4 v1 = *(const float4*)(ht8 + (size_t)cs[e+1]*8 + half*4);
    acc.x+=v0.x; acc.y+=v0.y; acc.z+=v0.z; acc.w+=v0.w;
    acc2.x+=v1.x; acc2.y+=v1.y; acc2.z+=v1.z; acc2.w+=v1.w;
  }
  if(e<e1){
    float4 v0 = *(const float4*)(ht8 + (size_t)cs[e]*8 + half*4);
    acc.x+=v0.x; acc.y+=v0.y; acc.z+=v0.z; acc.w+=v0.w;
  }
  acc.x+=acc2.x; acc.y+=acc2.y; acc.z+=acc2.z; acc.w+=acc2.w;
  float dv=dinv[node];
  float* ob = out + (size_t)node*5;
  if(half==0){
    ob[0] = fmaf(dv, acc.x, b2[0]);
    ob[1] = fmaf(dv, acc.y, b2[1]);
    ob[2] = fmaf(dv, acc.z, b2[2]);
    ob[3] = fmaf(dv, acc.w, b2[3]);
  } else {
    ob[4] = fmaf(dv, acc.x, b2[4]);
  }
}

// ---------------- launch ----------------

extern "C" void kernel_launch(void* const* d_in, const int* in_sizes, int n_in,
                              void* d_out, int out_size, void* d_ws, size_t ws_size,
                              hipStream_t stream){
  const float* x  = (const float*)d_in[0];
  const int*   ei = (const int*)  d_in[1];
  const float* W0 = (const float*)d_in[2];
  const float* b0 = (const float*)d_in[3];
  const float* W1 = (const float*)d_in[4];
  const float* b1 = (const float*)d_in[5];
  const float* W2 = (const float*)d_in[6];
  const float* b2 = (const float*)d_in[7];
  int n = in_sizes[0]/DF;
  int e = in_sizes[1]/2;
  const int* srcp = ei;
  const int* dstp = ei + e;

  char* ws = (char*)d_ws;
  size_t off=0;
  auto take=[&](size_t bytes)->char*{
    char* p = ws+off;
    off = (off+bytes+511)&~(size_t)511;
    return p;
  };
  int*   bcnt = (int*)  take((size_t)NB_MAX*4);
  int*   bcur = (int*)  take((size_t)NB_MAX*4);
  int*   rp   = (int*)  take((size_t)(n+1)*4);
  int*   csr  = (int*)  take((size_t)e*4);
  float* dinv = (float*)take((size_t)n*4);
  __half* WT0h = (__half*)take((size_t)DF*DF*2);
  __half* WT1h = (__half*)take((size_t)DF*DF*2);
  char*  bufA = take((size_t)n*DF*4);
  char*  bufB = take((size_t)n*DF*4);
  int*   binned = (int*)bufB;           // dead before first layer write of bufB
  __half* htH  = (__half*)bufA;         // per-layer dinv*(X@W), fp16
  __half* h1H  = (__half*)bufB;         // layer-1 output, fp16 (lower half of bufB)
  float*  ht8B = (float*)(bufB + (size_t)n*DF*2);  // layer-3 pre-agg, padded [n][8], upper half of bufB

  int nb   = (n + RB-1) >> RB_SHIFT;
  int ncb  = (e + CHUNK-1) / CHUNK;
  k_init      <<<128, 256, 0, stream>>>(W0, W1, WT0h, WT1h, bcnt, bcur);
  k_bhist     <<<ncb, 256, 0, stream>>>(dstp, bcnt, e);
  k_binscatter<<<ncb, 256, 0, stream>>>(srcp, dstp, bcnt, bcur, binned, e);
  k_localcsr  <<<nb,  256, 0, stream>>>(binned, bcnt, rp, csr, dinv, n, e);

  int ngb = (n+127)/128;
  int nab = (n+15)/16;
  // layer 1: ht0 = dinv*(x@W0) fp16 (bufA) ; h1 = relu(dinv*agg(ht0)+b0) fp16 (bufB lower)
  k_gemm128m<false><<<ngb, 512, 0, stream>>>(x,   WT0h, dinv, htH, n);
  k_agg128h        <<<nab, 256, 0, stream>>>(htH, rp, csr, dinv, b0, h1H, n);
  // layer 2: ht1 = dinv*(h1@W1) fp16 (bufA) ; ht8 = dinv*(relu(dinv*agg(ht1)+b1)@W2) (bufB upper)
  k_gemm128m<true> <<<ngb, 512, 0, stream>>>(h1H, WT1h, dinv, htH, n);
  k_agg_w2         <<<nab, 256, 0, stream>>>(htH, rp, csr, dinv, b1, W2, ht8B, n);
  // layer 3: out = dinv*agg(ht8)+b2
  k_agg5    <<<((n*2)+255)/256, 256, 0, stream>>>(ht8B, rp, csr, dinv, b2, (float*)d_out, n);
}

// Round 21
// 245.032 us; speedup vs baseline: 1.1697x; 1.1697x over previous
//
#include <hip/hip_runtime.h>
#include <hip/hip_fp16.h>

#define DF 128
#define RB 512            // nodes per bucket (power of two)
#define RB_SHIFT 9
#define NB_MAX 256        // supports n <= 131072
#define CHUNK 8192        // edges per binning block (2048 measured worse, R16)

struct h2x4 { __half2 a, b, c, d; }; // 16 bytes = 8 halves

typedef _Float16 hh2 __attribute__((ext_vector_type(2)));
struct alignas(16) hv8 { hh2 a, b, c, d; };   // 16 bytes = 8 halves

typedef _Float16 f16x8 __attribute__((ext_vector_type(8)));
typedef float f32x4 __attribute__((ext_vector_type(4)));

// ---------------- init: transpose W0,W1 -> fp16 WT, zero bcnt/bcur ----------------

__global__ void k_init(const float* __restrict__ W0, const float* __restrict__ W1,
                       __half* __restrict__ WT0h, __half* __restrict__ WT1h,
                       int* __restrict__ bcnt, int* __restrict__ bcur){
  int t = threadIdx.x;
  if(blockIdx.x==0) bcnt[t]=0;
  if(blockIdx.x==1) bcur[t]=0;
  int i = blockIdx.x*256 + t;            // 0..32767
  int k = (i&16383)>>7, c = i&127;
  if(i<16384) WT0h[(size_t)c*DF+k] = __float2half(W0[(size_t)k*DF+c]);
  else        WT1h[(size_t)c*DF+k] = __float2half(W1[(size_t)k*DF+c]);
}

// ---------------- CSR build (bucketed, coalesced; binned packed: (s<<9)|(d&511)) ----------------

__global__ void k_bhist(const int* __restrict__ dst, int* __restrict__ bcnt, int e){
  __shared__ int h[NB_MAX];
  int t = threadIdx.x;
  h[t] = 0;
  __syncthreads();
  int base = blockIdx.x*CHUNK;
  for(int k=0;k<CHUNK/256;k++){
    int i = base + t + k*256;
    if(i<e) atomicAdd(&h[dst[i]>>RB_SHIFT], 1);
  }
  __syncthreads();
  if(h[t]) atomicAdd(&bcnt[t], h[t]);
}

__launch_bounds__(256)
__global__ void k_binscatter(const int* __restrict__ src, const int* __restrict__ dst,
                             const int* __restrict__ bcnt, int* __restrict__ bcur,
                             int* __restrict__ binned, int e){
  __shared__ int h[NB_MAX];
  __shared__ int lexcl[NB_MAX];
  __shared__ int lcur[NB_MAX];
  __shared__ int gbase[NB_MAX];
  __shared__ int gscn[NB_MAX];
  __shared__ int2 pairs[CHUNK];
  int t = threadIdx.x;
  int c0 = blockIdx.x*CHUNK;
  int cc = min(CHUNK, e - c0);
  h[t]=0;
  int gc = bcnt[t];
  gscn[t] = gc;
  __syncthreads();
  for(int off=1; off<256; off<<=1){
    int v = (t>=off)? gscn[t-off]:0;
    __syncthreads();
    gscn[t]+=v;
    __syncthreads();
  }
  int gex = gscn[t] - gc;
  for(int k=0;k<CHUNK/256;k++){
    int i = t + k*256;
    if(i<cc) atomicAdd(&h[dst[c0+i]>>RB_SHIFT], 1);
  }
  __syncthreads();
  int hc = h[t];
  lexcl[t]=hc;
  __syncthreads();
  for(int off=1; off<256; off<<=1){
    int v = (t>=off)? lexcl[t-off]:0;
    __syncthreads();
    lexcl[t]+=v;
    __syncthreads();
  }
  int incl = lexcl[t];
  lexcl[t] = incl - hc;
  lcur[t]  = incl - hc;
  gbase[t] = hc ? (gex + atomicAdd(&bcur[t], hc)) : 0;
  __syncthreads();
  for(int k=0;k<CHUNK/256;k++){
    int i = t + k*256;
    if(i<cc){
      int d = dst[c0+i], s = src[c0+i];
      int lp = atomicAdd(&lcur[d>>RB_SHIFT], 1);
      pairs[lp] = make_int2(d, s);
    }
  }
  __syncthreads();
  for(int k=0;k<CHUNK/256;k++){
    int p = t + k*256;
    if(p<cc){
      int2 pr = pairs[p];
      int b = pr.x>>RB_SHIFT;
      int packed = (pr.y<<RB_SHIFT) | (pr.x & (RB-1));
      binned[gbase[b] + (p - lexcl[b])] = packed;
    }
  }
}

__launch_bounds__(256)
__global__ void k_localcsr(const int* __restrict__ binned, const int* __restrict__ bcnt,
                           int* __restrict__ rp, int* __restrict__ csr,
                           float* __restrict__ dinv, int n, int e){
  __shared__ int cnt[RB];
  __shared__ int sh[256];
  __shared__ int cur[RB];
  __shared__ int sb[257];
  int b = blockIdx.x, t = threadIdx.x;
  int node0 = b<<RB_SHIFT;
  int gc = bcnt[t];
  sh[t] = gc;
  __syncthreads();
  for(int off=1; off<256; off<<=1){
    int v = (t>=off)? sh[t-off]:0;
    __syncthreads();
    sh[t]+=v;
    __syncthreads();
  }
  sb[t+1]=sh[t];
  if(t==0) sb[0]=0;
  __syncthreads();
  int e0 = sb[b], e1 = sb[b+1];
  cnt[t]=0; cnt[t+256]=0;
  __syncthreads();
  for(int i=e0+t; i<e1; i+=256)
    atomicAdd(&cnt[binned[i] & (RB-1)], 1);
  __syncthreads();
  int c0 = cnt[2*t], c1 = cnt[2*t+1];
  int s = c0+c1;
  sh[t]=s;
  __syncthreads();
  for(int off=1; off<256; off<<=1){
    int v = (t>=off)? sh[t-off]:0;
    __syncthreads();
    sh[t]+=v;
    __syncthreads();
  }
  int excl = sh[t]-s;
  int g0 = node0+2*t, g1 = node0+2*t+1;
  if(g0<n){ rp[g0]=e0+excl;    dinv[g0]=rsqrtf((float)(c0+1)); }
  if(g1<n){ rp[g1]=e0+excl+c0; dinv[g1]=rsqrtf((float)(c1+1)); }
  cur[2*t]=excl; cur[2*t+1]=excl+c0;
  if(b==0 && t==0) rp[n]=e;
  __syncthreads();
  for(int i=e0+t; i<e1; i+=256){
    int pk = binned[i];
    int lp = atomicAdd(&cur[pk & (RB-1)], 1);
    csr[e0+lp] = ((unsigned)pk) >> RB_SHIFT;
  }
}

// ---------------- GEMM via MFMA (R19 version): ht = dinv .* (X @ W) -> fp16 ----------------
// 128 rows/block, 512 threads (8 waves). W staged ONCE per block in LDS (the R20
// global-B variant was -41us: lanes hit 16 distinct lines per fragment).
// Epilogue transposes D through xsh (freed after MFMA) -> coalesced 16B stores.

template<bool IN_HALF>
__launch_bounds__(512)
__global__ void k_gemm128m(const void* __restrict__ Xp, const __half* __restrict__ WTh,
                           const float* __restrict__ dinv, __half* __restrict__ out, int n){
  __shared__ hh2 xsh[128][68];   // 128 rows x 136 halves (pad -> 2-way bank, free)
  __shared__ hh2 wth[128][68];
  int t = threadIdx.x;
  int row0 = blockIdx.x*128;
  for(int idx=t; idx<128*16; idx+=512){
    int c = idx>>4, k8 = idx&15;
    *(hv8*)&wth[c][k8*4] = *(const hv8*)(WTh + (size_t)c*DF + k8*8);
  }
  for(int idx=t; idx<128*16; idx+=512){
    int r = idx>>4, k8 = idx&15;
    int gr = row0+r;
    hv8 u;
    if(gr<n){
      if constexpr(IN_HALF){
        u = *(const hv8*)((const __half*)Xp + (size_t)gr*DF + k8*8);
      } else {
        const float* xp = (const float*)Xp + (size_t)gr*DF + k8*8;
        float4 v0 = *(const float4*)xp;
        float4 v1 = *(const float4*)(xp+4);
        u.a = hh2{(_Float16)v0.x,(_Float16)v0.y};
        u.b = hh2{(_Float16)v0.z,(_Float16)v0.w};
        u.c = hh2{(_Float16)v1.x,(_Float16)v1.y};
        u.d = hh2{(_Float16)v1.z,(_Float16)v1.w};
      }
    } else {
      u.a = hh2{0,0}; u.b = u.a; u.c = u.a; u.d = u.a;
    }
    *(hv8*)&xsh[r][k8*4] = u;
  }
  __syncthreads();
  int wave = t>>6, lane = t&63;
  int lrow = lane&15, lk = lane>>4;
  f32x4 acc[8];
  #pragma unroll
  for(int i=0;i<8;i++) acc[i] = (f32x4){0.f,0.f,0.f,0.f};
  #pragma unroll
  for(int kc=0;kc<4;kc++){
    int koff = kc*16 + lk*4;
    f16x8 afr = *(const f16x8*)&xsh[wave*16 + lrow][koff];
    #pragma unroll
    for(int nt=0;nt<8;nt++){
      f16x8 bfr = *(const f16x8*)&wth[nt*16 + lrow][koff];
      acc[nt] = __builtin_amdgcn_mfma_f32_16x16x32_f16(afr, bfr, acc[nt], 0, 0, 0);
    }
  }
  __syncthreads();   // xsh reads done; safe to overwrite
  __half* xh = (__half*)&xsh[0][0];    // row stride 136 halves
  int brow = wave*16 + lk*4;
  #pragma unroll
  for(int r=0;r<4;r++){
    int gr = row0 + brow + r;
    float dv = (gr<n)? dinv[gr] : 0.f;
    #pragma unroll
    for(int nt=0;nt<8;nt++){
      xh[(size_t)(brow+r)*136 + nt*16 + lrow] = __float2half(dv*acc[nt][r]);
    }
  }
  __syncthreads();
  for(int idx=t; idx<128*16; idx+=512){
    int r = idx>>4, k8 = idx&15;
    int gr = row0+r;
    if(gr<n) *(hv8*)(out + (size_t)gr*DF + k8*8) = *(const hv8*)&xsh[r][k8*4];
  }
}

// ---------------- Layer-1 aggregate (fp16 gather -> fp16 out) ----------------

__launch_bounds__(256)
__global__ void k_agg128h(const __half* __restrict__ ht, const int* __restrict__ rp,
                          const int* __restrict__ cs, const float* __restrict__ dinv,
                          const float* __restrict__ bias, __half* __restrict__ outp, int n){
  int t=threadIdx.x;
  int node = blockIdx.x*16 + (t>>4);
  if(node>=n) return;
  int l8 = (t&15)*8;
  h2x4 sv = *(const h2x4*)(ht + (size_t)node*DF + l8);   // self
  float2 P0=__half22float2(sv.a), P1=__half22float2(sv.b),
         P2=__half22float2(sv.c), P3=__half22float2(sv.d);
  float2 Q0=make_float2(0.f,0.f), Q1=Q0, Q2=Q0, Q3=Q0;
  int e0=rp[node], e1=rp[node+1];
  int e=e0;
  for(; e+3<e1; e+=4){
    int s0=cs[e], s1=cs[e+1], s2=cs[e+2], s3=cs[e+3];
    h2x4 u0 = *(const h2x4*)(ht + (size_t)s0*DF + l8);
    h2x4 u1 = *(const h2x4*)(ht + (size_t)s1*DF + l8);
    h2x4 u2 = *(const h2x4*)(ht + (size_t)s2*DF + l8);
    h2x4 u3 = *(const h2x4*)(ht + (size_t)s3*DF + l8);
    float2 f;
    f=__half22float2(u0.a); P0.x+=f.x; P0.y+=f.y;
    f=__half22float2(u0.b); P1.x+=f.x; P1.y+=f.y;
    f=__half22float2(u0.c); P2.x+=f.x; P2.y+=f.y;
    f=__half22float2(u0.d); P3.x+=f.x; P3.y+=f.y;
    f=__half22float2(u1.a); Q0.x+=f.x; Q0.y+=f.y;
    f=__half22float2(u1.b); Q1.x+=f.x; Q1.y+=f.y;
    f=__half22float2(u1.c); Q2.x+=f.x; Q2.y+=f.y;
    f=__half22float2(u1.d); Q3.x+=f.x; Q3.y+=f.y;
    f=__half22float2(u2.a); P0.x+=f.x; P0.y+=f.y;
    f=__half22float2(u2.b); P1.x+=f.x; P1.y+=f.y;
    f=__half22float2(u2.c); P2.x+=f.x; P2.y+=f.y;
    f=__half22float2(u2.d); P3.x+=f.x; P3.y+=f.y;
    f=__half22float2(u3.a); Q0.x+=f.x; Q0.y+=f.y;
    f=__half22float2(u3.b); Q1.x+=f.x; Q1.y+=f.y;
    f=__half22float2(u3.c); Q2.x+=f.x; Q2.y+=f.y;
    f=__half22float2(u3.d); Q3.x+=f.x; Q3.y+=f.y;
  }
  for(; e<e1; e++){
    h2x4 u0 = *(const h2x4*)(ht + (size_t)cs[e]*DF + l8);
    float2 f;
    f=__half22float2(u0.a); P0.x+=f.x; P0.y+=f.y;
    f=__half22float2(u0.b); P1.x+=f.x; P1.y+=f.y;
    f=__half22float2(u0.c); P2.x+=f.x; P2.y+=f.y;
    f=__half22float2(u0.d); P3.x+=f.x; P3.y+=f.y;
  }
  float dv=dinv[node];
  const float4 bz0 = *(const float4*)(bias + l8);
  const float4 bz1 = *(const float4*)(bias + l8 + 4);
  float4 o0, o1;
  o0.x = fmaxf(fmaf(dv, P0.x+Q0.x, bz0.x), 0.f);
  o0.y = fmaxf(fmaf(dv, P0.y+Q0.y, bz0.y), 0.f);
  o0.z = fmaxf(fmaf(dv, P1.x+Q1.x, bz0.z), 0.f);
  o0.w = fmaxf(fmaf(dv, P1.y+Q1.y, bz0.w), 0.f);
  o1.x = fmaxf(fmaf(dv, P2.x+Q2.x, bz1.x), 0.f);
  o1.y = fmaxf(fmaf(dv, P2.y+Q2.y, bz1.y), 0.f);
  o1.z = fmaxf(fmaf(dv, P3.x+Q3.x, bz1.z), 0.f);
  o1.w = fmaxf(fmaf(dv, P3.y+Q3.y, bz1.w), 0.f);
  h2x4 st;
  st.a = __floats2half2_rn(o0.x, o0.y);
  st.b = __floats2half2_rn(o0.z, o0.w);
  st.c = __floats2half2_rn(o1.x, o1.y);
  st.d = __floats2half2_rn(o1.z, o1.w);
  *(h2x4*)(outp + (size_t)node*DF + l8) = st;
}

// ---------------- Layer-2 aggregate fused with W2: ht8 = dinv*(relu(...)@W2) ----------------

__launch_bounds__(256)
__global__ void k_agg_w2(const __half* __restrict__ ht, const int* __restrict__ rp,
                         const int* __restrict__ cs, const float* __restrict__ dinv,
                         const float* __restrict__ bias, const float* __restrict__ W2,
                         float* __restrict__ ht8, int n){
  int t=threadIdx.x;
  int node = blockIdx.x*16 + (t>>4);
  if(node>=n) return;
  int l8 = (t&15)*8;
  h2x4 sv = *(const h2x4*)(ht + (size_t)node*DF + l8);   // self
  float2 P0=__half22float2(sv.a), P1=__half22float2(sv.b),
         P2=__half22float2(sv.c), P3=__half22float2(sv.d);
  float2 Q0=make_float2(0.f,0.f), Q1=Q0, Q2=Q0, Q3=Q0;
  int e0=rp[node], e1=rp[node+1];
  int e=e0;
  for(; e+3<e1; e+=4){
    int s0=cs[e], s1=cs[e+1], s2=cs[e+2], s3=cs[e+3];
    h2x4 u0 = *(const h2x4*)(ht + (size_t)s0*DF + l8);
    h2x4 u1 = *(const h2x4*)(ht + (size_t)s1*DF + l8);
    h2x4 u2 = *(const h2x4*)(ht + (size_t)s2*DF + l8);
    h2x4 u3 = *(const h2x4*)(ht + (size_t)s3*DF + l8);
    float2 f;
    f=__half22float2(u0.a); P0.x+=f.x; P0.y+=f.y;
    f=__half22float2(u0.b); P1.x+=f.x; P1.y+=f.y;
    f=__half22float2(u0.c); P2.x+=f.x; P2.y+=f.y;
    f=__half22float2(u0.d); P3.x+=f.x; P3.y+=f.y;
    f=__half22float2(u1.a); Q0.x+=f.x; Q0.y+=f.y;
    f=__half22float2(u1.b); Q1.x+=f.x; Q1.y+=f.y;
    f=__half22float2(u1.c); Q2.x+=f.x; Q2.y+=f.y;
    f=__half22float2(u1.d); Q3.x+=f.x; Q3.y+=f.y;
    f=__half22float2(u2.a); P0.x+=f.x; P0.y+=f.y;
    f=__half22float2(u2.b); P1.x+=f.x; P1.y+=f.y;
    f=__half22float2(u2.c); P2.x+=f.x; P2.y+=f.y;
    f=__half22float2(u2.d); P3.x+=f.x; P3.y+=f.y;
    f=__half22float2(u3.a); Q0.x+=f.x; Q0.y+=f.y;
    f=__half22float2(u3.b); Q1.x+=f.x; Q1.y+=f.y;
    f=__half22float2(u3.c); Q2.x+=f.x; Q2.y+=f.y;
    f=__half22float2(u3.d); Q3.x+=f.x; Q3.y+=f.y;
  }
  for(; e<e1; e++){
    h2x4 u0 = *(const h2x4*)(ht + (size_t)cs[e]*DF + l8);
    float2 f;
    f=__half22float2(u0.a); P0.x+=f.x; P0.y+=f.y;
    f=__half22float2(u0.b); P1.x+=f.x; P1.y+=f.y;
    f=__half22float2(u0.c); P2.x+=f.x; P2.y+=f.y;
    f=__half22float2(u0.d); P3.x+=f.x; P3.y+=f.y;
  }
  float dv=dinv[node];
  const float4 bz0 = *(const float4*)(bias + l8);
  const float4 bz1 = *(const float4*)(bias + l8 + 4);
  float h0 = fmaxf(fmaf(dv, P0.x+Q0.x, bz0.x), 0.f);
  float h1 = fmaxf(fmaf(dv, P0.y+Q0.y, bz0.y), 0.f);
  float h2 = fmaxf(fmaf(dv, P1.x+Q1.x, bz0.z), 0.f);
  float h3 = fmaxf(fmaf(dv, P1.y+Q1.y, bz0.w), 0.f);
  float h4 = fmaxf(fmaf(dv, P2.x+Q2.x, bz1.x), 0.f);
  float h5 = fmaxf(fmaf(dv, P2.y+Q2.y, bz1.y), 0.f);
  float h6 = fmaxf(fmaf(dv, P3.x+Q3.x, bz1.z), 0.f);
  float h7 = fmaxf(fmaf(dv, P3.y+Q3.y, bz1.w), 0.f);
  const float* w2r = W2 + (size_t)l8*5;
  float p0,p1,p2,p3,p4;
  p0 = h0*w2r[0];  p1 = h0*w2r[1];  p2 = h0*w2r[2];  p3 = h0*w2r[3];  p4 = h0*w2r[4];
  p0 = fmaf(h1,w2r[5], p0); p1 = fmaf(h1,w2r[6], p1); p2 = fmaf(h1,w2r[7], p2); p3 = fmaf(h1,w2r[8], p3); p4 = fmaf(h1,w2r[9], p4);
  p0 = fmaf(h2,w2r[10],p0); p1 = fmaf(h2,w2r[11],p1); p2 = fmaf(h2,w2r[12],p2); p3 = fmaf(h2,w2r[13],p3); p4 = fmaf(h2,w2r[14],p4);
  p0 = fmaf(h3,w2r[15],p0); p1 = fmaf(h3,w2r[16],p1); p2 = fmaf(h3,w2r[17],p2); p3 = fmaf(h3,w2r[18],p3); p4 = fmaf(h3,w2r[19],p4);
  p0 = fmaf(h4,w2r[20],p0); p1 = fmaf(h4,w2r[21],p1); p2 = fmaf(h4,w2r[22],p2); p3 = fmaf(h4,w2r[23],p3); p4 = fmaf(h4,w2r[24],p4);
  p0 = fmaf(h5,w2r[25],p0); p1 = fmaf(h5,w2r[26],p1); p2 = fmaf(h5,w2r[27],p2); p3 = fmaf(h5,w2r[28],p3); p4 = fmaf(h5,w2r[29],p4);
  p0 = fmaf(h6,w2r[30],p0); p1 = fmaf(h6,w2r[31],p1); p2 = fmaf(h6,w2r[32],p2); p3 = fmaf(h6,w2r[33],p3); p4 = fmaf(h6,w2r[34],p4);
  p0 = fmaf(h7,w2r[35],p0); p1 = fmaf(h7,w2r[36],p1); p2 = fmaf(h7,w2r[37],p2); p3 = fmaf(h7,w2r[38],p3); p4 = fmaf(h7,w2r[39],p4);
  #pragma unroll
  for(int off=8; off>=1; off>>=1){
    p0 += __shfl_xor(p0, off, 16);
    p1 += __shfl_xor(p1, off, 16);
    p2 += __shfl_xor(p2, off, 16);
    p3 += __shfl_xor(p3, off, 16);
    p4 += __shfl_xor(p4, off, 16);
  }
  if((t&15)==0){
    float* ob = ht8 + (size_t)node*8;
    *(float4*)ob     = make_float4(dv*p0, dv*p1, dv*p2, dv*p3);
    *(float4*)(ob+4) = make_float4(dv*p4, 0.f, 0.f, 0.f);
  }
}

// ---------------- Final aggregate: 2 threads/node, float4 from padded L2-resident ht8 ----------------

__global__ void k_agg5(const float* __restrict__ ht8, const int* __restrict__ rp,
                       const int* __restrict__ cs, const float* __restrict__ dinv,
                       const float* __restrict__ b2, float* __restrict__ out, int n){
  int idx = blockIdx.x*256+threadIdx.x;
  int node = idx>>1, half = idx&1;
  if(node>=n) return;
  float4 acc = *(const float4*)(ht8 + (size_t)node*8 + half*4);
  int e0=rp[node], e1=rp[node+1];
  int e=e0;
  float4 acc2 = make_float4(0.f,0.f,0.f,0.f);
  for(; e+1<e1; e+=2){
    float4 v0 = *(const float4*)(ht8 + (size_t)cs[e  ]*8 + half*4);
    float4 v1 = *(const float4*)(ht8 + (size_t)cs[e+1]*8 + half*4);
    acc.x+=v0.x; acc.y+=v0.y; acc.z+=v0.z; acc.w+=v0.w;
    acc2.x+=v1.x; acc2.y+=v1.y; acc2.z+=v1.z; acc2.w+=v1.w;
  }
  if(e<e1){
    float4 v0 = *(const float4*)(ht8 + (size_t)cs[e]*8 + half*4);
    acc.x+=v0.x; acc.y+=v0.y; acc.z+=v0.z; acc.w+=v0.w;
  }
  acc.x+=acc2.x; acc.y+=acc2.y; acc.z+=acc2.z; acc.w+=acc2.w;
  float dv=dinv[node];
  float* ob = out + (size_t)node*5;
  if(half==0){
    ob[0] = fmaf(dv, acc.x, b2[0]);
    ob[1] = fmaf(dv, acc.y, b2[1]);
    ob[2] = fmaf(dv, acc.z, b2[2]);
    ob[3] = fmaf(dv, acc.w, b2[3]);
  } else {
    ob[4] = fmaf(dv, acc.x, b2[4]);
  }
}

// ---------------- launch ----------------

extern "C" void kernel_launch(void* const* d_in, const int* in_sizes, int n_in,
                              void* d_out, int out_size, void* d_ws, size_t ws_size,
                              hipStream_t stream){
  const float* x  = (const float*)d_in[0];
  const int*   ei = (const int*)  d_in[1];
  const float* W0 = (const float*)d_in[2];
  const float* b0 = (const float*)d_in[3];
  const float* W1 = (const float*)d_in[4];
  const float* b1 = (const float*)d_in[5];
  const float* W2 = (const float*)d_in[6];
  const float* b2 = (const float*)d_in[7];
  int n = in_sizes[0]/DF;
  int e = in_sizes[1]/2;
  const int* srcp = ei;
  const int* dstp = ei + e;

  char* ws = (char*)d_ws;
  size_t off=0;
  auto take=[&](size_t bytes)->char*{
    char* p = ws+off;
    off = (off+bytes+511)&~(size_t)511;
    return p;
  };
  int*   bcnt = (int*)  take((size_t)NB_MAX*4);
  int*   bcur = (int*)  take((size_t)NB_MAX*4);
  int*   rp   = (int*)  take((size_t)(n+1)*4);
  int*   csr  = (int*)  take((size_t)e*4);
  float* dinv = (float*)take((size_t)n*4);
  __half* WT0h = (__half*)take((size_t)DF*DF*2);
  __half* WT1h = (__half*)take((size_t)DF*DF*2);
  char*  bufA = take((size_t)n*DF*4);
  char*  bufB = take((size_t)n*DF*4);
  int*   binned = (int*)bufB;           // dead before first layer write of bufB
  __half* htH  = (__half*)bufA;         // per-layer dinv*(X@W), fp16
  __half* h1H  = (__half*)bufB;         // layer-1 output, fp16 (lower half of bufB)
  float*  ht8B = (float*)(bufB + (size_t)n*DF*2);  // layer-3 pre-agg, padded [n][8], upper half of bufB

  int nb   = (n + RB-1) >> RB_SHIFT;
  int ncb  = (e + CHUNK-1) / CHUNK;
  k_init      <<<128, 256, 0, stream>>>(W0, W1, WT0h, WT1h, bcnt, bcur);
  k_bhist     <<<ncb, 256, 0, stream>>>(dstp, bcnt, e);
  k_binscatter<<<ncb, 256, 0, stream>>>(srcp, dstp, bcnt, bcur, binned, e);
  k_localcsr  <<<nb,  256, 0, stream>>>(binned, bcnt, rp, csr, dinv, n, e);

  int ngb = (n+127)/128;
  int nab = (n+15)/16;
  // layer 1: ht0 = dinv*(x@W0) fp16 (bufA) ; h1 = relu(dinv*agg(ht0)+b0) fp16 (bufB lower)
  k_gemm128m<false><<<ngb, 512, 0, stream>>>(x,   WT0h, dinv, htH, n);
  k_agg128h        <<<nab, 256, 0, stream>>>(htH, rp, csr, dinv, b0, h1H, n);
  // layer 2: ht1 = dinv*(h1@W1) fp16 (bufA) ; ht8 = dinv*(relu(dinv*agg(ht1)+b1)@W2) (bufB upper)
  k_gemm128m<true> <<<ngb, 512, 0, stream>>>(h1H, WT1h, dinv, htH, n);
  k_agg_w2         <<<nab, 256, 0, stream>>>(htH, rp, csr, dinv, b1, W2, ht8B, n);
  // layer 3: out = dinv*agg(ht8)+b2
  k_agg5    <<<((n*2)+255)/256, 256, 0, stream>>>(ht8B, rp, csr, dinv, b2, (float*)d_out, n);
}